// Round 5
// baseline (225.142 us; speedup 1.0000x reference)
//
#include <hip/hip_runtime.h>
#include <stdint.h>

// SRU layer fused pipeline:
//  1) cvt:   w_ufr f32 -> bf16
//  2) ln:    LayerNorm rows (T*B=16384, D=1024) -> x_norm bf16
//  3) gemm:  256x256 tile, A staged via 4-slot LDS ring (swizzled, 0-conflict),
//            B loaded DIRECT global->VGPR (2-slot register rotation, depth-2
//            prefetch), unified counted vmcnt(6) ledger, 1 barrier/K-step,
//            XCD-aware block swizzle. bf16 MFMA, f32 acc, hardsigmoid fused.
//  4) scan1: per-chunk (A = prod f, B) linear-recurrence composition
//  5) scan2: sequential scan over 32 chunks -> chunk-start c, c_last
//  6) scan3: within-chunk recurrence + softsign + output mix + residual

#define T_SEQ 2048
#define BATCH 8
#define DIM 1024
#define M_SZ (T_SEQ * BATCH)   // 16384
#define N_SZ (3 * DIM)         // 3072
#define K_SZ DIM               // 1024
#define NCHUNK 32
#define CLEN (T_SEQ / NCHUNK)  // 64

#define GBM 256
#define GBN 256
#define GBK 32
#define NKT (K_SZ / GBK)       // 32 K-steps
#define NBX (N_SZ / GBN)       // 12
#define NWG (NBX * (M_SZ / GBM))  // 768 blocks; 768 % 8 == 0 -> simple XCD swizzle ok

typedef __attribute__((ext_vector_type(8))) __bf16 bf16x8;
typedef __attribute__((ext_vector_type(4))) float f32x4;

__device__ __forceinline__ unsigned short f2bf(float f) {
  unsigned int u = __float_as_uint(f);
  u += 0x7FFFu + ((u >> 16) & 1u);   // round-to-nearest-even
  return (unsigned short)(u >> 16);
}
__device__ __forceinline__ float bf2f(unsigned short s) {
  return __uint_as_float(((unsigned int)s) << 16);
}
__device__ __forceinline__ void gload16(const void* g, void* l) {
  __builtin_amdgcn_global_load_lds(
      (__attribute__((address_space(1))) void*)const_cast<void*>(g),
      (__attribute__((address_space(3))) void*)l, 16, 0, 0);
}

// ---------------- 1) weight f32 -> bf16 ----------------
__global__ __launch_bounds__(256) void cvt_kernel(const float* __restrict__ w,
                                                  unsigned short* __restrict__ wb) {
  const int i = blockIdx.x * 256 + threadIdx.x;
  const float4 v = reinterpret_cast<const float4*>(w)[i];
  ushort4 o;
  o.x = f2bf(v.x); o.y = f2bf(v.y); o.z = f2bf(v.z); o.w = f2bf(v.w);
  reinterpret_cast<ushort4*>(wb)[i] = o;
}

// ---------------- 2) LayerNorm ----------------
__global__ __launch_bounds__(256) void ln_kernel(const float* __restrict__ x,
                                                 const float* __restrict__ gamma,
                                                 const float* __restrict__ beta,
                                                 unsigned short* __restrict__ xn) {
  const int row = blockIdx.x;
  const int tid = threadIdx.x;
  const float4 v = reinterpret_cast<const float4*>(x + (size_t)row * DIM)[tid];
  float s = v.x + v.y + v.z + v.w;
  float q = v.x * v.x + v.y * v.y + v.z * v.z + v.w * v.w;
#pragma unroll
  for (int off = 32; off > 0; off >>= 1) {
    s += __shfl_down(s, off);
    q += __shfl_down(q, off);
  }
  __shared__ float sbuf[8];
  const int wv = tid >> 6, ln = tid & 63;
  if (ln == 0) { sbuf[wv] = s; sbuf[4 + wv] = q; }
  __syncthreads();
  s = sbuf[0] + sbuf[1] + sbuf[2] + sbuf[3];
  q = sbuf[4] + sbuf[5] + sbuf[6] + sbuf[7];
  const float mu = s * (1.0f / DIM);
  const float rstd = rsqrtf(q * (1.0f / DIM) - mu * mu + 1e-5f);
  const float4 g = reinterpret_cast<const float4*>(gamma)[tid];
  const float4 b = reinterpret_cast<const float4*>(beta)[tid];
  ushort4 o;
  o.x = f2bf((v.x - mu) * rstd * g.x + b.x);
  o.y = f2bf((v.y - mu) * rstd * g.y + b.y);
  o.z = f2bf((v.z - mu) * rstd * g.z + b.z);
  o.w = f2bf((v.w - mu) * rstd * g.w + b.w);
  reinterpret_cast<ushort4*>(xn + (size_t)row * DIM)[tid] = o;
}

// ---------------- 3) GEMM: C[m,n] = sum_k A[m,k] * W[n,k], bf16 MFMA ----------------
// 512 threads (8 waves, 2Mx4N), per-wave 128x64 output.
// A: 4-slot LDS ring (4 x 16 KB), depth-3 prefetch via global_load_lds, XOR
//    slot-swizzle (0 bank conflicts, verified r3).
// B: DIRECT global->VGPR. 2-slot bf16x8[4] register rotation, loaded 2 steps
//    ahead, issued AFTER the MFMA cluster that consumes the slot (WAR-safe:
//    in-order issue means MFMA operands are read before the load writes back).
// Unified vmcnt ledger per step kt: issue STAGE_A(kt+3) [2] ... MFMA ...
// BLOAD(kt+2) [4]; end-of-step vmcnt(6) == everything older than BLOAD(kt+1)
// done => A(kt+1) in LDS and B(kt+1) regs valid. Tail: 6,6,...,6,4,0.
__global__ __launch_bounds__(512) void gemm_kernel(const unsigned short* __restrict__ A,
                                                   const unsigned short* __restrict__ W,
                                                   unsigned short* __restrict__ C) {
  __shared__ unsigned short smem[4 * GBM * GBK];   // 65536 B, A only
  const int tid = threadIdx.x;
  const int lane = tid & 63;
  const int wid = tid >> 6;                 // 0..7
  const int wm = wid >> 2, wn = wid & 3;    // 2 x 4 wave grid

  // XCD-aware swizzle: consecutive logical wgs (sharing an A-panel) land on
  // the same XCD's L2. 768 % 8 == 0 -> bijective simple form.
  const int wg = (blockIdx.x & 7) * (NWG / 8) + (blockIdx.x >> 3);
  const int bn0 = (wg % NBX) * GBN;
  const int bm0 = (wg / NBX) * GBM;

  // A staging: tile 256x32 = 16 KB = 2 block-wide gloads (512 thr x 16 B).
  // gload h covers rows [h*128, h*128+128); wave wid rows h*128+wid*16+l/4,
  // slot l%4; global col-slot pre-swizzled (l&3)^((l>>3)&3)  [r3-verified].
  const int stgRow = wid * 16 + (lane >> 2);
  const int stgCol = ((lane & 3) ^ ((lane >> 3) & 3)) * 8;
  const unsigned short* gA0 = A + (size_t)(bm0 + stgRow) * K_SZ + stgCol;
  const unsigned short* gA1 = gA0 + (size_t)128 * K_SZ;
  unsigned short* sA0 = smem + (wid * 16) * GBK;
  unsigned short* sA1 = smem + (128 + wid * 16) * GBK;

#define STAGE_A(bufi, t) do {                                      \
    const size_t ko_ = (size_t)(t) * GBK;                          \
    gload16(gA0 + ko_, sA0 + (bufi) * (GBM * GBK));                \
    gload16(gA1 + ko_, sA1 + (bufi) * (GBM * GBK));                \
  } while (0)

  const int fr = lane & 15;          // fragment row (A) / col (B,C)
  const int ko8 = ((lane >> 4) ^ ((fr >> 1) & 3)) * 8;   // swizzled k-slot (LDS read)

  // B direct-load voffsets (bytes into W): row = bn0 + wn*64 + j*16 + fr,
  // within-row k byte = t*64 + (lane>>4)*16.
  unsigned int bvo[4];
#pragma unroll
  for (int j = 0; j < 4; j++)
    bvo[j] = (unsigned int)(bn0 + wn * 64 + j * 16 + fr) * (K_SZ * 2) + (lane >> 4) * 16;

  bf16x8 b0[4], b1[4];
#define BLOAD(breg, t) do {                                        \
    const unsigned int to_ = (unsigned int)(t) * (GBK * 2);        \
    asm volatile("global_load_dwordx4 %0, %1, %2"                  \
        : "=v"(breg[0]) : "v"(bvo[0] + to_), "s"(W));              \
    asm volatile("global_load_dwordx4 %0, %1, %2"                  \
        : "=v"(breg[1]) : "v"(bvo[1] + to_), "s"(W));              \
    asm volatile("global_load_dwordx4 %0, %1, %2"                  \
        : "=v"(breg[2]) : "v"(bvo[2] + to_), "s"(W));              \
    asm volatile("global_load_dwordx4 %0, %1, %2"                  \
        : "=v"(breg[3]) : "v"(bvo[3] + to_), "s"(W));              \
  } while (0)

  f32x4 acc[8][4] = {};

  // prologue: A slots 0,1,2 (6 gloads); B steps 0,1 (8 reg loads)
  STAGE_A(0, 0);
  STAGE_A(1, 1);
  STAGE_A(2, 2);
  BLOAD(b0, 0);
  BLOAD(b1, 1);
  asm volatile("s_waitcnt vmcnt(4)" ::: "memory");   // A(0) + B(0) landed
  __builtin_amdgcn_sched_barrier(0);
  __builtin_amdgcn_s_barrier();
  asm volatile("" ::: "memory");

#define BODY(kt, breg, VM) do {                                              \
    const int cur_ = (kt) & 3;                                               \
    if ((kt) <= NKT - 4) STAGE_A(((kt) + 3) & 3, (kt) + 3);                  \
    const unsigned short* sa_ = smem + cur_ * (GBM * GBK);                   \
    bf16x8 af_[8];                                                           \
    _Pragma("unroll")                                                        \
    for (int i = 0; i < 8; i++)                                              \
      af_[i] = *(const bf16x8*)&sa_[(wm * 128 + i * 16 + fr) * GBK + ko8];   \
    __builtin_amdgcn_s_setprio(1);                                           \
    _Pragma("unroll")                                                        \
    for (int i = 0; i < 8; i++)                                              \
      _Pragma("unroll")                                                      \
      for (int j = 0; j < 4; j++)                                            \
        acc[i][j] = __builtin_amdgcn_mfma_f32_16x16x32_bf16(af_[i], breg[j], \
                                                            acc[i][j], 0, 0, 0); \
    __builtin_amdgcn_s_setprio(0);                                           \
    if ((kt) <= NKT - 3) BLOAD(breg, (kt) + 2);                              \
    asm volatile("s_waitcnt vmcnt(" #VM ")" ::: "memory");                   \
    __builtin_amdgcn_sched_barrier(0);                                       \
    __builtin_amdgcn_s_barrier();                                            \
    asm volatile("" ::: "memory");                                           \
  } while (0)

  // main loop: steps 0..27 (even count), no tail conditions active
  for (int kt = 0; kt < NKT - 4; kt += 2) {
    BODY(kt, b0, 6);
    BODY(kt + 1, b1, 6);
  }
  // peeled tail: steps 28..31
  BODY(NKT - 4, b0, 6);   // stages A(31), loads B(30)
  BODY(NKT - 3, b1, 4);   // loads B(31)
  BODY(NKT - 2, b0, 0);   // drain
  {                        // last step: no wait/barrier needed after
    const unsigned short* sa_ = smem + ((NKT - 1) & 3) * (GBM * GBK);
    bf16x8 af_[8];
#pragma unroll
    for (int i = 0; i < 8; i++)
      af_[i] = *(const bf16x8*)&sa_[(wm * 128 + i * 16 + fr) * GBK + ko8];
#pragma unroll
    for (int i = 0; i < 8; i++)
#pragma unroll
      for (int j = 0; j < 4; j++)
        acc[i][j] = __builtin_amdgcn_mfma_f32_16x16x32_bf16(af_[i], b1[j], acc[i][j], 0, 0, 0);
  }
#undef BODY
#undef BLOAD
#undef STAGE_A

  // epilogue: C/D layout col = lane&15, row = (lane>>4)*4 + reg  [m89-verified]
  const int gate = (bn0 >= DIM);  // whole 256-col tile lies in u, or in f/r region
  const int fq = lane >> 4;
#pragma unroll
  for (int i = 0; i < 8; i++) {
#pragma unroll
    for (int j = 0; j < 4; j++) {
      const int col = bn0 + wn * 64 + j * 16 + fr;
      size_t base = (size_t)(bm0 + wm * 128 + i * 16 + fq * 4) * N_SZ + col;
#pragma unroll
      for (int r = 0; r < 4; r++) {
        float v = acc[i][j][r];
        if (gate) v = fminf(fmaxf(v * (1.0f / 6.0f) + 0.5f, 0.0f), 1.0f);
        C[base + (size_t)r * N_SZ] = f2bf(v);
      }
    }
  }
}

// ---------------- 4) per-chunk recurrence composition ----------------
__global__ __launch_bounds__(256) void scan1_kernel(const unsigned short* __restrict__ ufr,
                                                    float* __restrict__ Ac,
                                                    float* __restrict__ Bc) {
  const int lin = blockIdx.x * 256 + threadIdx.x;   // NCHUNK*B*D
  const int d = lin & (DIM - 1);
  const int b = (lin >> 10) & (BATCH - 1);
  const int g = lin >> 13;
  const unsigned short* p = ufr + (size_t)(g * CLEN) * (BATCH * N_SZ) + (size_t)b * N_SZ + d;
  float Aa = 1.0f, Bb = 0.0f;
#pragma unroll 8
  for (int t = 0; t < CLEN; t++) {
    const float u = bf2f(p[0]);
    const float f = bf2f(p[DIM]);      // already hardsigmoid'ed
    Aa *= f;
    Bb = f * Bb + (1.0f - f) * u;
    p += BATCH * N_SZ;
  }
  Ac[lin] = Aa;
  Bc[lin] = Bb;
}

// ---------------- 5) scan over chunks ----------------
__global__ __launch_bounds__(256) void scan2_kernel(const float* __restrict__ Ac,
                                                    const float* __restrict__ Bc,
                                                    const float* __restrict__ c0,
                                                    float* __restrict__ cstart,
                                                    float* __restrict__ clast) {
  const int lin = blockIdx.x * 256 + threadIdx.x;   // B*D = 8192
  float c = c0[lin];
#pragma unroll
  for (int g = 0; g < NCHUNK; g++) {
    cstart[g * (BATCH * DIM) + lin] = c;
    c = Ac[g * (BATCH * DIM) + lin] * c + Bc[g * (BATCH * DIM) + lin];
  }
  clast[lin] = c;
}

// ---------------- 6) within-chunk recurrence + epilogue ----------------
__global__ __launch_bounds__(256) void scan3_kernel(const unsigned short* __restrict__ ufr,
                                                    const unsigned short* __restrict__ xn,
                                                    const float* __restrict__ x,
                                                    const float* __restrict__ cstart,
                                                    float* __restrict__ out) {
  const int lin = blockIdx.x * 256 + threadIdx.x;
  const int d = lin & (DIM - 1);
  const int b = (lin >> 10) & (BATCH - 1);
  const int g = lin >> 13;
  float c = cstart[g * (BATCH * DIM) + b * DIM + d];
  const unsigned short* p = ufr + (size_t)(g * CLEN) * (BATCH * N_SZ) + (size_t)b * N_SZ + d;
  size_t xo = (size_t)(g * CLEN) * (BATCH * DIM) + (size_t)b * DIM + d;
#pragma unroll 4
  for (int t = 0; t < CLEN; t++) {
    const float u = bf2f(p[0]);
    const float f = bf2f(p[DIM]);
    const float r = bf2f(p[2 * DIM]);
    c = f * c + (1.0f - f) * u;
    const float ts = c / (1.0f + fabsf(c));   // softsign
    const float xv = bf2f(xn[xo]);
    out[xo] = x[xo] + r * ts + (1.0f - r) * xv;
    p += BATCH * N_SZ;
    xo += BATCH * DIM;
  }
}

extern "C" void kernel_launch(void* const* d_in, const int* in_sizes, int n_in,
                              void* d_out, int out_size, void* d_ws, size_t ws_size,
                              hipStream_t stream) {
  const float* x = (const float*)d_in[0];
  const float* c0 = (const float*)d_in[1];
  const float* w = (const float*)d_in[2];
  const float* gamma = (const float*)d_in[3];
  const float* beta = (const float*)d_in[4];
  float* out = (float*)d_out;
  float* clast = out + (size_t)M_SZ * DIM;   // second output, flat-concatenated

  // workspace layout (total ~143.7 MB)
  char* ws = (char*)d_ws;
  unsigned short* xn = (unsigned short*)ws;                        //  33,554,432 B
  unsigned short* ufr = (unsigned short*)(ws + 33554432ull);       // 100,663,296 B
  float* Ac = (float*)(ws + 134217728ull);                         //   1,048,576 B
  float* Bc = (float*)(ws + 135266304ull);                         //   1,048,576 B
  float* cst = (float*)(ws + 136314880ull);                        //   1,048,576 B
  unsigned short* wb = (unsigned short*)(ws + 137363456ull);       //   6,291,456 B

  cvt_kernel<<<(N_SZ * K_SZ / 4) / 256, 256, 0, stream>>>(w, wb);
  ln_kernel<<<M_SZ, 256, 0, stream>>>(x, gamma, beta, xn);
  gemm_kernel<<<NWG, 512, 0, stream>>>(xn, wb, ufr);
  scan1_kernel<<<(NCHUNK * BATCH * DIM) / 256, 256, 0, stream>>>(ufr, Ac, Bc);
  scan2_kernel<<<(BATCH * DIM) / 256, 256, 0, stream>>>(Ac, Bc, c0, cst, clast);
  scan3_kernel<<<(NCHUNK * BATCH * DIM) / 256, 256, 0, stream>>>(ufr, xn, x, cst, out);
}

// Round 6
// 199.272 us; speedup vs baseline: 1.1298x; 1.1298x over previous
//
#include <hip/hip_runtime.h>
#include <stdint.h>

// SRU layer fused pipeline (round 6):
//  1) cvt:   w_ufr f32 -> bf16
//  2) ln:    LayerNorm rows -> x_norm bf16 + per-row mu/rstd (f32)
//  3) gemm:  r3-verified 256x256 / BK=32 / 4-slot ring / counted vmcnt /
//            XOR swizzle (0 conflicts) + XCD-aware block swizzle (r5-verified
//            FETCH cut). bf16 MFMA, f32 acc, hardsigmoid fused.
//  4) scan1: per-chunk (A = prod f, B) composition — 4-wide vectorized
//  5) scan2: sequential scan over 32 chunks -> chunk-start c, c_last
//  6) scan3: within-chunk recurrence + epilogue — 4-wide, x_norm recomputed
//            in f32 from x/mu/rstd (xn read eliminated)

#define T_SEQ 2048
#define BATCH 8
#define DIM 1024
#define M_SZ (T_SEQ * BATCH)   // 16384
#define N_SZ (3 * DIM)         // 3072
#define K_SZ DIM               // 1024
#define NCHUNK 32
#define CLEN (T_SEQ / NCHUNK)  // 64

#define GBM 256
#define GBN 256
#define GBK 32
#define NKT (K_SZ / GBK)          // 32 K-steps
#define NBX (N_SZ / GBN)          // 12
#define NWG (NBX * (M_SZ / GBM))  // 768; 768 % 8 == 0 -> bijective XCD swizzle

typedef __attribute__((ext_vector_type(8))) __bf16 bf16x8;
typedef __attribute__((ext_vector_type(4))) float f32x4;

__device__ __forceinline__ unsigned short f2bf(float f) {
  unsigned int u = __float_as_uint(f);
  u += 0x7FFFu + ((u >> 16) & 1u);   // round-to-nearest-even
  return (unsigned short)(u >> 16);
}
__device__ __forceinline__ float bf2f(unsigned short s) {
  return __uint_as_float(((unsigned int)s) << 16);
}
__device__ __forceinline__ void gload16(const void* g, void* l) {
  __builtin_amdgcn_global_load_lds(
      (__attribute__((address_space(1))) void*)const_cast<void*>(g),
      (__attribute__((address_space(3))) void*)l, 16, 0, 0);
}

// ---------------- 1) weight f32 -> bf16 ----------------
__global__ __launch_bounds__(256) void cvt_kernel(const float* __restrict__ w,
                                                  unsigned short* __restrict__ wb) {
  const int i = blockIdx.x * 256 + threadIdx.x;
  const float4 v = reinterpret_cast<const float4*>(w)[i];
  ushort4 o;
  o.x = f2bf(v.x); o.y = f2bf(v.y); o.z = f2bf(v.z); o.w = f2bf(v.w);
  reinterpret_cast<ushort4*>(wb)[i] = o;
}

// ---------------- 2) LayerNorm (+ mu/rstd out) ----------------
__global__ __launch_bounds__(256) void ln_kernel(const float* __restrict__ x,
                                                 const float* __restrict__ gamma,
                                                 const float* __restrict__ beta,
                                                 unsigned short* __restrict__ xn,
                                                 float* __restrict__ muO,
                                                 float* __restrict__ rsO) {
  const int row = blockIdx.x;
  const int tid = threadIdx.x;
  const float4 v = reinterpret_cast<const float4*>(x + (size_t)row * DIM)[tid];
  float s = v.x + v.y + v.z + v.w;
  float q = v.x * v.x + v.y * v.y + v.z * v.z + v.w * v.w;
#pragma unroll
  for (int off = 32; off > 0; off >>= 1) {
    s += __shfl_down(s, off);
    q += __shfl_down(q, off);
  }
  __shared__ float sbuf[8];
  const int wv = tid >> 6, ln = tid & 63;
  if (ln == 0) { sbuf[wv] = s; sbuf[4 + wv] = q; }
  __syncthreads();
  s = sbuf[0] + sbuf[1] + sbuf[2] + sbuf[3];
  q = sbuf[4] + sbuf[5] + sbuf[6] + sbuf[7];
  const float mu = s * (1.0f / DIM);
  const float rstd = rsqrtf(q * (1.0f / DIM) - mu * mu + 1e-5f);
  if (tid == 0) { muO[row] = mu; rsO[row] = rstd; }
  const float4 g = reinterpret_cast<const float4*>(gamma)[tid];
  const float4 b = reinterpret_cast<const float4*>(beta)[tid];
  ushort4 o;
  o.x = f2bf((v.x - mu) * rstd * g.x + b.x);
  o.y = f2bf((v.y - mu) * rstd * g.y + b.y);
  o.z = f2bf((v.z - mu) * rstd * g.z + b.z);
  o.w = f2bf((v.w - mu) * rstd * g.w + b.w);
  reinterpret_cast<ushort4*>(xn + (size_t)row * DIM)[tid] = o;
}

// ---------------- 3) GEMM: C[m,n] = sum_k A[m,k] * W[n,k], bf16 MFMA ----------------
// r3-verified structure: 256x256 tile, BK=32, 512 threads (8 waves, 2Mx4N),
// per-wave 128x64 output, 4-slot LDS ring (128 KiB), depth-3 prefetch,
// s_waitcnt vmcnt(8) steady state, one raw s_barrier per K-step, XOR
// slot-swizzle (0 bank conflicts). NEW: XCD-aware block swizzle (r5-verified
// FETCH 151->94 MB): consecutive logical wgs share an A-panel on one XCD L2.
__global__ __launch_bounds__(512) void gemm_kernel(const unsigned short* __restrict__ A,
                                                   const unsigned short* __restrict__ W,
                                                   unsigned short* __restrict__ C) {
  __shared__ unsigned short smem[2 * 4 * GBM * GBK];   // 131072 B
  const int tid = threadIdx.x;
  const int lane = tid & 63;
  const int wid = tid >> 6;                 // 0..7
  const int wm = wid >> 2, wn = wid & 3;    // 2 x 4 wave grid

  // XCD swizzle: XCD x gets contiguous wg chunk [x*96, x*96+96) = 8 A-panels.
  const int wg = (blockIdx.x & 7) * (NWG / 8) + (blockIdx.x >> 3);
  const int bn0 = (wg % NBX) * GBN;
  const int bm0 = (wg / NBX) * GBM;

  // staging map (r3-verified): wave wid owns rows [wid*32, wid*32+32) of each
  // 256-row tile, as 2 gload16 of 16 rows (1024 B) each. lane l -> LDS row
  // +l/4, LDS slot l%4; global col-slot pre-swizzled (l&3)^((l>>3)&3).
  const int stgRow = wid * 32 + (lane >> 2);
  const int stgCol = ((lane & 3) ^ ((lane >> 3) & 3)) * 8;
  const unsigned short* gA = A + (size_t)(bm0 + stgRow) * K_SZ + stgCol;
  const unsigned short* gB = W + (size_t)(bn0 + stgRow) * K_SZ + stgCol;
  unsigned short* sAb = smem + wid * 32 * GBK;             // wave-uniform LDS base
  unsigned short* sBb = smem + 4 * GBM * GBK + wid * 32 * GBK;

#define STAGE(bufi, t) do {                                        \
    const size_t ko_ = (size_t)(t) * GBK;                          \
    unsigned short* sa_ = sAb + (bufi) * (GBM * GBK);              \
    unsigned short* sb_ = sBb + (bufi) * (GBM * GBK);              \
    gload16(gA + ko_, sa_);                                        \
    gload16(gA + ko_ + (size_t)16 * K_SZ, sa_ + 16 * GBK);         \
    gload16(gB + ko_, sb_);                                        \
    gload16(gB + ko_ + (size_t)16 * K_SZ, sb_ + 16 * GBK);         \
  } while (0)

  f32x4 acc[8][4] = {};
  const int fr = lane & 15;          // fragment row (A) / col (B,C)
  // swizzled k-slot element offset: slot = lane>>4, XOR (fr>>1)&3
  const int ko8 = ((lane >> 4) ^ ((fr >> 1) & 3)) * 8;

  // prologue: K-steps 0,1,2 -> slots 0,1,2 (12 loads/thread)
  STAGE(0, 0);
  STAGE(1, 1);
  STAGE(2, 2);
  asm volatile("s_waitcnt vmcnt(8)" ::: "memory");   // slot 0 landed
  __builtin_amdgcn_s_barrier();
  asm volatile("" ::: "memory");

  for (int kt = 0; kt < NKT; ++kt) {
    const int cur = kt & 3;
    if (kt < NKT - 3) STAGE((kt + 3) & 3, kt + 3);   // slot reads done at kt-1

    const unsigned short* sa = smem + cur * (GBM * GBK);
    const unsigned short* sb = smem + 4 * GBM * GBK + cur * (GBM * GBK);
    bf16x8 af[8], bf[4];
#pragma unroll
    for (int i = 0; i < 8; i++)
      af[i] = *(const bf16x8*)&sa[(wm * 128 + i * 16 + fr) * GBK + ko8];
#pragma unroll
    for (int j = 0; j < 4; j++)
      bf[j] = *(const bf16x8*)&sb[(wn * 64 + j * 16 + fr) * GBK + ko8];

    __builtin_amdgcn_s_setprio(1);
#pragma unroll
    for (int i = 0; i < 8; i++)
#pragma unroll
      for (int j = 0; j < 4; j++)
        acc[i][j] = __builtin_amdgcn_mfma_f32_16x16x32_bf16(af[i], bf[j], acc[i][j], 0, 0, 0);
    __builtin_amdgcn_s_setprio(0);

    // counted wait: slot kt+1 landed; keep kt+2,kt+3 in flight
    if (kt < NKT - 3)       asm volatile("s_waitcnt vmcnt(8)" ::: "memory");
    else if (kt == NKT - 3) asm volatile("s_waitcnt vmcnt(4)" ::: "memory");
    else if (kt == NKT - 2) asm volatile("s_waitcnt vmcnt(0)" ::: "memory");
    if (kt < NKT - 1) {
      __builtin_amdgcn_s_barrier();
      asm volatile("" ::: "memory");
    }
  }
#undef STAGE

  // epilogue: C/D layout col = lane&15, row = (lane>>4)*4 + reg  [m89-verified]
  const int gate = (bn0 >= DIM);  // whole 256-col tile lies in u, or in f/r region
  const int fq = lane >> 4;
#pragma unroll
  for (int i = 0; i < 8; i++) {
#pragma unroll
    for (int j = 0; j < 4; j++) {
      const int col = bn0 + wn * 64 + j * 16 + fr;
      size_t base = (size_t)(bm0 + wm * 128 + i * 16 + fq * 4) * N_SZ + col;
#pragma unroll
      for (int r = 0; r < 4; r++) {
        float v = acc[i][j][r];
        if (gate) v = fminf(fmaxf(v * (1.0f / 6.0f) + 0.5f, 0.0f), 1.0f);
        C[base + (size_t)r * N_SZ] = f2bf(v);
      }
    }
  }
}

// ---------------- 4) per-chunk recurrence composition (4-wide) ----------------
__global__ __launch_bounds__(256) void scan1_kernel(const unsigned short* __restrict__ ufr,
                                                    float* __restrict__ Ac,
                                                    float* __restrict__ Bc) {
  const int lin = blockIdx.x * 256 + threadIdx.x;   // NCHUNK*B*D/4 = 65536
  const int d0 = (lin & 255) << 2;
  const int b = (lin >> 8) & (BATCH - 1);
  const int g = lin >> 11;
  const unsigned short* p = ufr + (size_t)(g * CLEN) * (BATCH * N_SZ) + (size_t)b * N_SZ + d0;
  float Aa0 = 1.0f, Aa1 = 1.0f, Aa2 = 1.0f, Aa3 = 1.0f;
  float Bb0 = 0.0f, Bb1 = 0.0f, Bb2 = 0.0f, Bb3 = 0.0f;
#pragma unroll 4
  for (int t = 0; t < CLEN; t++) {
    const ushort4 uu = *reinterpret_cast<const ushort4*>(p);
    const ushort4 ff = *reinterpret_cast<const ushort4*>(p + DIM);
    const float f0 = bf2f(ff.x), f1 = bf2f(ff.y), f2 = bf2f(ff.z), f3 = bf2f(ff.w);
    Aa0 *= f0; Aa1 *= f1; Aa2 *= f2; Aa3 *= f3;
    Bb0 = f0 * Bb0 + (1.0f - f0) * bf2f(uu.x);
    Bb1 = f1 * Bb1 + (1.0f - f1) * bf2f(uu.y);
    Bb2 = f2 * Bb2 + (1.0f - f2) * bf2f(uu.z);
    Bb3 = f3 * Bb3 + (1.0f - f3) * bf2f(uu.w);
    p += BATCH * N_SZ;
  }
  const int o = g * (BATCH * DIM) + b * DIM + d0;
  *reinterpret_cast<float4*>(&Ac[o]) = make_float4(Aa0, Aa1, Aa2, Aa3);
  *reinterpret_cast<float4*>(&Bc[o]) = make_float4(Bb0, Bb1, Bb2, Bb3);
}

// ---------------- 5) scan over chunks ----------------
__global__ __launch_bounds__(256) void scan2_kernel(const float* __restrict__ Ac,
                                                    const float* __restrict__ Bc,
                                                    const float* __restrict__ c0,
                                                    float* __restrict__ cstart,
                                                    float* __restrict__ clast) {
  const int lin = blockIdx.x * 256 + threadIdx.x;   // B*D = 8192
  float c = c0[lin];
#pragma unroll
  for (int g = 0; g < NCHUNK; g++) {
    cstart[g * (BATCH * DIM) + lin] = c;
    c = Ac[g * (BATCH * DIM) + lin] * c + Bc[g * (BATCH * DIM) + lin];
  }
  clast[lin] = c;
}

// ---------------- 6) within-chunk recurrence + epilogue (4-wide, f32 x_norm) --
__global__ __launch_bounds__(256) void scan3_kernel(const unsigned short* __restrict__ ufr,
                                                    const float* __restrict__ x,
                                                    const float* __restrict__ cstart,
                                                    const float* __restrict__ muA,
                                                    const float* __restrict__ rsA,
                                                    const float* __restrict__ gamma,
                                                    const float* __restrict__ beta,
                                                    float* __restrict__ out) {
  const int lin = blockIdx.x * 256 + threadIdx.x;   // NCHUNK*B*D/4 = 65536
  const int d0 = (lin & 255) << 2;
  const int b = (lin >> 8) & (BATCH - 1);
  const int g = lin >> 11;
  const float4 cs = *reinterpret_cast<const float4*>(&cstart[g * (BATCH * DIM) + b * DIM + d0]);
  float c0 = cs.x, c1 = cs.y, c2 = cs.z, c3 = cs.w;
  const float4 gm = *reinterpret_cast<const float4*>(&gamma[d0]);
  const float4 bt = *reinterpret_cast<const float4*>(&beta[d0]);
  const unsigned short* p = ufr + (size_t)(g * CLEN) * (BATCH * N_SZ) + (size_t)b * N_SZ + d0;
  size_t xo = (size_t)(g * CLEN) * (BATCH * DIM) + (size_t)b * DIM + d0;
  int row = g * CLEN * BATCH + b;
#pragma unroll 2
  for (int t = 0; t < CLEN; t++) {
    const ushort4 uu = *reinterpret_cast<const ushort4*>(p);
    const ushort4 ff = *reinterpret_cast<const ushort4*>(p + DIM);
    const ushort4 rr = *reinterpret_cast<const ushort4*>(p + 2 * DIM);
    const float4 xv = *reinterpret_cast<const float4*>(&x[xo]);
    const float mu = muA[row], rs = rsA[row];
    float o[4];
    {
      const float f = bf2f(ff.x), r = bf2f(rr.x);
      const float xnv = (xv.x - mu) * rs * gm.x + bt.x;
      c0 = f * c0 + (1.0f - f) * bf2f(uu.x);
      o[0] = xv.x + r * (c0 / (1.0f + fabsf(c0))) + (1.0f - r) * xnv;
    }
    {
      const float f = bf2f(ff.y), r = bf2f(rr.y);
      const float xnv = (xv.y - mu) * rs * gm.y + bt.y;
      c1 = f * c1 + (1.0f - f) * bf2f(uu.y);
      o[1] = xv.y + r * (c1 / (1.0f + fabsf(c1))) + (1.0f - r) * xnv;
    }
    {
      const float f = bf2f(ff.z), r = bf2f(rr.z);
      const float xnv = (xv.z - mu) * rs * gm.z + bt.z;
      c2 = f * c2 + (1.0f - f) * bf2f(uu.z);
      o[2] = xv.z + r * (c2 / (1.0f + fabsf(c2))) + (1.0f - r) * xnv;
    }
    {
      const float f = bf2f(ff.w), r = bf2f(rr.w);
      const float xnv = (xv.w - mu) * rs * gm.w + bt.w;
      c3 = f * c3 + (1.0f - f) * bf2f(uu.w);
      o[3] = xv.w + r * (c3 / (1.0f + fabsf(c3))) + (1.0f - r) * xnv;
    }
    *reinterpret_cast<float4*>(&out[xo]) = make_float4(o[0], o[1], o[2], o[3]);
    p += BATCH * N_SZ;
    xo += BATCH * DIM;
    row += BATCH;
  }
}

extern "C" void kernel_launch(void* const* d_in, const int* in_sizes, int n_in,
                              void* d_out, int out_size, void* d_ws, size_t ws_size,
                              hipStream_t stream) {
  const float* x = (const float*)d_in[0];
  const float* c0 = (const float*)d_in[1];
  const float* w = (const float*)d_in[2];
  const float* gamma = (const float*)d_in[3];
  const float* beta = (const float*)d_in[4];
  float* out = (float*)d_out;
  float* clast = out + (size_t)M_SZ * DIM;   // second output, flat-concatenated

  // workspace layout (total ~143.8 MB)
  char* ws = (char*)d_ws;
  unsigned short* xn = (unsigned short*)ws;                        //  33,554,432 B
  unsigned short* ufr = (unsigned short*)(ws + 33554432ull);       // 100,663,296 B
  float* Ac = (float*)(ws + 134217728ull);                         //   1,048,576 B
  float* Bc = (float*)(ws + 135266304ull);                         //   1,048,576 B
  float* cst = (float*)(ws + 136314880ull);                        //   1,048,576 B
  unsigned short* wb = (unsigned short*)(ws + 137363456ull);       //   6,291,456 B
  float* muA = (float*)(ws + 143654912ull);                        //      65,536 B
  float* rsA = (float*)(ws + 143720448ull);                        //      65,536 B

  cvt_kernel<<<(N_SZ * K_SZ / 4) / 256, 256, 0, stream>>>(w, wb);
  ln_kernel<<<M_SZ, 256, 0, stream>>>(x, gamma, beta, xn, muA, rsA);
  gemm_kernel<<<NWG, 512, 0, stream>>>(xn, wb, ufr);
  scan1_kernel<<<(NCHUNK * BATCH * DIM / 4) / 256, 256, 0, stream>>>(ufr, Ac, Bc);
  scan2_kernel<<<(BATCH * DIM) / 256, 256, 0, stream>>>(Ac, Bc, c0, cst, clast);
  scan3_kernel<<<(NCHUNK * BATCH * DIM / 4) / 256, 256, 0, stream>>>(
      ufr, x, cst, muA, rsA, gamma, beta, out);
}

// Round 7
// 193.605 us; speedup vs baseline: 1.1629x; 1.0293x over previous
//
#include <hip/hip_runtime.h>
#include <stdint.h>

// SRU layer fused pipeline (round 7):
//  1) cvt:   w_ufr f32 -> bf16
//  2) ln:    LayerNorm rows -> x_norm bf16 + per-row mu/rstd (f32)
//  3) gemm:  r6-verified 256x256 / BK=32 / 4-slot ring / counted vmcnt /
//            XOR swizzle (0 conflicts) / XCD block swizzle (FETCH-cut).
//            Epilogue now writes compact [M][D] arrays: u as bf16,
//            f/r gates hardsigmoid'ed + quantized to u8 (1/255 fixed point).
//  4) scan1: per-chunk (A = prod f, B) composition — 4-wide vectorized
//  5) scan2: sequential scan over 32 chunks -> chunk-start c, c_last
//  6) scan3: within-chunk recurrence + epilogue — 4-wide, x_norm recomputed
//            in f32 from x/mu/rstd

#define T_SEQ 2048
#define BATCH 8
#define DIM 1024
#define M_SZ (T_SEQ * BATCH)   // 16384
#define N_SZ (3 * DIM)         // 3072
#define K_SZ DIM               // 1024
#define NCHUNK 32
#define CLEN (T_SEQ / NCHUNK)  // 64

#define GBM 256
#define GBN 256
#define GBK 32
#define NKT (K_SZ / GBK)          // 32 K-steps
#define NBX (N_SZ / GBN)          // 12
#define NWG (NBX * (M_SZ / GBM))  // 768; 768 % 8 == 0 -> bijective XCD swizzle

typedef __attribute__((ext_vector_type(8))) __bf16 bf16x8;
typedef __attribute__((ext_vector_type(4))) float f32x4;

__device__ __forceinline__ unsigned short f2bf(float f) {
  unsigned int u = __float_as_uint(f);
  u += 0x7FFFu + ((u >> 16) & 1u);   // round-to-nearest-even
  return (unsigned short)(u >> 16);
}
__device__ __forceinline__ float bf2f(unsigned short s) {
  return __uint_as_float(((unsigned int)s) << 16);
}
__device__ __forceinline__ void gload16(const void* g, void* l) {
  __builtin_amdgcn_global_load_lds(
      (__attribute__((address_space(1))) void*)const_cast<void*>(g),
      (__attribute__((address_space(3))) void*)l, 16, 0, 0);
}

// ---------------- 1) weight f32 -> bf16 ----------------
__global__ __launch_bounds__(256) void cvt_kernel(const float* __restrict__ w,
                                                  unsigned short* __restrict__ wb) {
  const int i = blockIdx.x * 256 + threadIdx.x;
  const float4 v = reinterpret_cast<const float4*>(w)[i];
  ushort4 o;
  o.x = f2bf(v.x); o.y = f2bf(v.y); o.z = f2bf(v.z); o.w = f2bf(v.w);
  reinterpret_cast<ushort4*>(wb)[i] = o;
}

// ---------------- 2) LayerNorm (+ mu/rstd out) ----------------
__global__ __launch_bounds__(256) void ln_kernel(const float* __restrict__ x,
                                                 const float* __restrict__ gamma,
                                                 const float* __restrict__ beta,
                                                 unsigned short* __restrict__ xn,
                                                 float* __restrict__ muO,
                                                 float* __restrict__ rsO) {
  const int row = blockIdx.x;
  const int tid = threadIdx.x;
  const float4 v = reinterpret_cast<const float4*>(x + (size_t)row * DIM)[tid];
  float s = v.x + v.y + v.z + v.w;
  float q = v.x * v.x + v.y * v.y + v.z * v.z + v.w * v.w;
#pragma unroll
  for (int off = 32; off > 0; off >>= 1) {
    s += __shfl_down(s, off);
    q += __shfl_down(q, off);
  }
  __shared__ float sbuf[8];
  const int wv = tid >> 6, ln = tid & 63;
  if (ln == 0) { sbuf[wv] = s; sbuf[4 + wv] = q; }
  __syncthreads();
  s = sbuf[0] + sbuf[1] + sbuf[2] + sbuf[3];
  q = sbuf[4] + sbuf[5] + sbuf[6] + sbuf[7];
  const float mu = s * (1.0f / DIM);
  const float rstd = rsqrtf(q * (1.0f / DIM) - mu * mu + 1e-5f);
  if (tid == 0) { muO[row] = mu; rsO[row] = rstd; }
  const float4 g = reinterpret_cast<const float4*>(gamma)[tid];
  const float4 b = reinterpret_cast<const float4*>(beta)[tid];
  ushort4 o;
  o.x = f2bf((v.x - mu) * rstd * g.x + b.x);
  o.y = f2bf((v.y - mu) * rstd * g.y + b.y);
  o.z = f2bf((v.z - mu) * rstd * g.z + b.z);
  o.w = f2bf((v.w - mu) * rstd * g.w + b.w);
  reinterpret_cast<ushort4*>(xn + (size_t)row * DIM)[tid] = o;
}

// ---------------- 3) GEMM: C[m,n] = sum_k A[m,k] * W[n,k], bf16 MFMA ----------------
// r6-verified structure: 256x256 tile, BK=32, 512 threads (8 waves, 2Mx4N),
// per-wave 128x64 output, 4-slot LDS ring (128 KiB), depth-3 prefetch,
// s_waitcnt vmcnt(8) steady state, one raw s_barrier per K-step, XOR
// slot-swizzle (0 bank conflicts, r3), XCD block swizzle (FETCH 151->94 MB, r5).
// Epilogue: region 0 (u) -> bf16 [M][D]; regions 1/2 (f/r) -> hardsigmoid
// quantized u8 [M][D].
__global__ __launch_bounds__(512) void gemm_kernel(const unsigned short* __restrict__ A,
                                                   const unsigned short* __restrict__ W,
                                                   unsigned short* __restrict__ U,
                                                   unsigned char* __restrict__ Fq,
                                                   unsigned char* __restrict__ Rq) {
  __shared__ unsigned short smem[2 * 4 * GBM * GBK];   // 131072 B
  const int tid = threadIdx.x;
  const int lane = tid & 63;
  const int wid = tid >> 6;                 // 0..7
  const int wm = wid >> 2, wn = wid & 3;    // 2 x 4 wave grid

  // XCD swizzle: XCD x gets contiguous wg chunk [x*96, x*96+96) = 8 A-panels.
  const int wg = (blockIdx.x & 7) * (NWG / 8) + (blockIdx.x >> 3);
  const int bn0 = (wg % NBX) * GBN;
  const int bm0 = (wg / NBX) * GBM;

  // staging map (r3-verified): wave wid owns rows [wid*32, wid*32+32) of each
  // 256-row tile, as 2 gload16 of 16 rows (1024 B) each. lane l -> LDS row
  // +l/4, LDS slot l%4; global col-slot pre-swizzled (l&3)^((l>>3)&3).
  const int stgRow = wid * 32 + (lane >> 2);
  const int stgCol = ((lane & 3) ^ ((lane >> 3) & 3)) * 8;
  const unsigned short* gA = A + (size_t)(bm0 + stgRow) * K_SZ + stgCol;
  const unsigned short* gB = W + (size_t)(bn0 + stgRow) * K_SZ + stgCol;
  unsigned short* sAb = smem + wid * 32 * GBK;             // wave-uniform LDS base
  unsigned short* sBb = smem + 4 * GBM * GBK + wid * 32 * GBK;

#define STAGE(bufi, t) do {                                        \
    const size_t ko_ = (size_t)(t) * GBK;                          \
    unsigned short* sa_ = sAb + (bufi) * (GBM * GBK);              \
    unsigned short* sb_ = sBb + (bufi) * (GBM * GBK);              \
    gload16(gA + ko_, sa_);                                        \
    gload16(gA + ko_ + (size_t)16 * K_SZ, sa_ + 16 * GBK);         \
    gload16(gB + ko_, sb_);                                        \
    gload16(gB + ko_ + (size_t)16 * K_SZ, sb_ + 16 * GBK);         \
  } while (0)

  f32x4 acc[8][4] = {};
  const int fr = lane & 15;          // fragment row (A) / col (B,C)
  // swizzled k-slot element offset: slot = lane>>4, XOR (fr>>1)&3
  const int ko8 = ((lane >> 4) ^ ((fr >> 1) & 3)) * 8;

  // prologue: K-steps 0,1,2 -> slots 0,1,2 (12 loads/thread)
  STAGE(0, 0);
  STAGE(1, 1);
  STAGE(2, 2);
  asm volatile("s_waitcnt vmcnt(8)" ::: "memory");   // slot 0 landed
  __builtin_amdgcn_s_barrier();
  asm volatile("" ::: "memory");

  for (int kt = 0; kt < NKT; ++kt) {
    const int cur = kt & 3;
    if (kt < NKT - 3) STAGE((kt + 3) & 3, kt + 3);   // slot reads done at kt-1

    const unsigned short* sa = smem + cur * (GBM * GBK);
    const unsigned short* sb = smem + 4 * GBM * GBK + cur * (GBM * GBK);
    bf16x8 af[8], bf[4];
#pragma unroll
    for (int i = 0; i < 8; i++)
      af[i] = *(const bf16x8*)&sa[(wm * 128 + i * 16 + fr) * GBK + ko8];
#pragma unroll
    for (int j = 0; j < 4; j++)
      bf[j] = *(const bf16x8*)&sb[(wn * 64 + j * 16 + fr) * GBK + ko8];

    __builtin_amdgcn_s_setprio(1);
#pragma unroll
    for (int i = 0; i < 8; i++)
#pragma unroll
      for (int j = 0; j < 4; j++)
        acc[i][j] = __builtin_amdgcn_mfma_f32_16x16x32_bf16(af[i], bf[j], acc[i][j], 0, 0, 0);
    __builtin_amdgcn_s_setprio(0);

    // counted wait: slot kt+1 landed; keep kt+2,kt+3 in flight
    if (kt < NKT - 3)       asm volatile("s_waitcnt vmcnt(8)" ::: "memory");
    else if (kt == NKT - 3) asm volatile("s_waitcnt vmcnt(4)" ::: "memory");
    else if (kt == NKT - 2) asm volatile("s_waitcnt vmcnt(0)" ::: "memory");
    if (kt < NKT - 1) {
      __builtin_amdgcn_s_barrier();
      asm volatile("" ::: "memory");
    }
  }
#undef STAGE

  // epilogue: C/D layout col = lane&15, row = (lane>>4)*4 + reg  [m89-verified]
  const int region = bn0 >> 10;   // 0:u  1:f  2:r  (tile fully inside a region)
  const int cb0 = bn0 & 1023;     // col base within region
  const int fq = lane >> 4;
  unsigned char* G = (region == 1) ? Fq : Rq;
#pragma unroll
  for (int i = 0; i < 8; i++) {
#pragma unroll
    for (int j = 0; j < 4; j++) {
      const int coln = cb0 + wn * 64 + j * 16 + fr;
      size_t base = (size_t)(bm0 + wm * 128 + i * 16 + fq * 4) * DIM + coln;
      if (region == 0) {
#pragma unroll
        for (int r = 0; r < 4; r++)
          U[base + (size_t)r * DIM] = f2bf(acc[i][j][r]);
      } else {
#pragma unroll
        for (int r = 0; r < 4; r++) {
          float v = fminf(fmaxf(acc[i][j][r] * (1.0f / 6.0f) + 0.5f, 0.0f), 1.0f);
          G[base + (size_t)r * DIM] = (unsigned char)(v * 255.0f + 0.5f);
        }
      }
    }
  }
}

// ---------------- 4) per-chunk recurrence composition (4-wide) ----------------
__global__ __launch_bounds__(256) void scan1_kernel(const unsigned short* __restrict__ U,
                                                    const unsigned char* __restrict__ Fq,
                                                    float* __restrict__ Ac,
                                                    float* __restrict__ Bc) {
  const int lin = blockIdx.x * 256 + threadIdx.x;   // NCHUNK*B*D/4 = 65536
  const int d0 = (lin & 255) << 2;
  const int b = (lin >> 8) & (BATCH - 1);
  const int g = lin >> 11;
  size_t off = (size_t)(g * CLEN) * (BATCH * DIM) + (size_t)b * DIM + d0;
  float Aa0 = 1.0f, Aa1 = 1.0f, Aa2 = 1.0f, Aa3 = 1.0f;
  float Bb0 = 0.0f, Bb1 = 0.0f, Bb2 = 0.0f, Bb3 = 0.0f;
#pragma unroll 4
  for (int t = 0; t < CLEN; t++) {
    const ushort4 uu = *reinterpret_cast<const ushort4*>(&U[off]);
    const uchar4 ff = *reinterpret_cast<const uchar4*>(&Fq[off]);
    const float f0 = ff.x * (1.0f / 255.0f), f1 = ff.y * (1.0f / 255.0f);
    const float f2 = ff.z * (1.0f / 255.0f), f3 = ff.w * (1.0f / 255.0f);
    Aa0 *= f0; Aa1 *= f1; Aa2 *= f2; Aa3 *= f3;
    Bb0 = f0 * Bb0 + (1.0f - f0) * bf2f(uu.x);
    Bb1 = f1 * Bb1 + (1.0f - f1) * bf2f(uu.y);
    Bb2 = f2 * Bb2 + (1.0f - f2) * bf2f(uu.z);
    Bb3 = f3 * Bb3 + (1.0f - f3) * bf2f(uu.w);
    off += BATCH * DIM;
  }
  const int o = g * (BATCH * DIM) + b * DIM + d0;
  *reinterpret_cast<float4*>(&Ac[o]) = make_float4(Aa0, Aa1, Aa2, Aa3);
  *reinterpret_cast<float4*>(&Bc[o]) = make_float4(Bb0, Bb1, Bb2, Bb3);
}

// ---------------- 5) scan over chunks ----------------
__global__ __launch_bounds__(256) void scan2_kernel(const float* __restrict__ Ac,
                                                    const float* __restrict__ Bc,
                                                    const float* __restrict__ c0,
                                                    float* __restrict__ cstart,
                                                    float* __restrict__ clast) {
  const int lin = blockIdx.x * 256 + threadIdx.x;   // B*D = 8192
  float c = c0[lin];
#pragma unroll
  for (int g = 0; g < NCHUNK; g++) {
    cstart[g * (BATCH * DIM) + lin] = c;
    c = Ac[g * (BATCH * DIM) + lin] * c + Bc[g * (BATCH * DIM) + lin];
  }
  clast[lin] = c;
}

// ---------------- 6) within-chunk recurrence + epilogue (4-wide, f32 x_norm) --
__global__ __launch_bounds__(256) void scan3_kernel(const unsigned short* __restrict__ U,
                                                    const unsigned char* __restrict__ Fq,
                                                    const unsigned char* __restrict__ Rq,
                                                    const float* __restrict__ x,
                                                    const float* __restrict__ cstart,
                                                    const float* __restrict__ muA,
                                                    const float* __restrict__ rsA,
                                                    const float* __restrict__ gamma,
                                                    const float* __restrict__ beta,
                                                    float* __restrict__ out) {
  const int lin = blockIdx.x * 256 + threadIdx.x;   // NCHUNK*B*D/4 = 65536
  const int d0 = (lin & 255) << 2;
  const int b = (lin >> 8) & (BATCH - 1);
  const int g = lin >> 11;
  const float4 cs = *reinterpret_cast<const float4*>(&cstart[g * (BATCH * DIM) + b * DIM + d0]);
  float c0 = cs.x, c1 = cs.y, c2 = cs.z, c3 = cs.w;
  const float4 gm = *reinterpret_cast<const float4*>(&gamma[d0]);
  const float4 bt = *reinterpret_cast<const float4*>(&beta[d0]);
  size_t xo = (size_t)(g * CLEN) * (BATCH * DIM) + (size_t)b * DIM + d0;
  int row = g * CLEN * BATCH + b;
#pragma unroll 2
  for (int t = 0; t < CLEN; t++) {
    const ushort4 uu = *reinterpret_cast<const ushort4*>(&U[xo]);
    const uchar4 ff = *reinterpret_cast<const uchar4*>(&Fq[xo]);
    const uchar4 rr = *reinterpret_cast<const uchar4*>(&Rq[xo]);
    const float4 xv = *reinterpret_cast<const float4*>(&x[xo]);
    const float mu = muA[row], rs = rsA[row];
    float o[4];
    {
      const float f = ff.x * (1.0f / 255.0f), r = rr.x * (1.0f / 255.0f);
      const float xnv = (xv.x - mu) * rs * gm.x + bt.x;
      c0 = f * c0 + (1.0f - f) * bf2f(uu.x);
      o[0] = xv.x + r * (c0 / (1.0f + fabsf(c0))) + (1.0f - r) * xnv;
    }
    {
      const float f = ff.y * (1.0f / 255.0f), r = rr.y * (1.0f / 255.0f);
      const float xnv = (xv.y - mu) * rs * gm.y + bt.y;
      c1 = f * c1 + (1.0f - f) * bf2f(uu.y);
      o[1] = xv.y + r * (c1 / (1.0f + fabsf(c1))) + (1.0f - r) * xnv;
    }
    {
      const float f = ff.z * (1.0f / 255.0f), r = rr.z * (1.0f / 255.0f);
      const float xnv = (xv.z - mu) * rs * gm.z + bt.z;
      c2 = f * c2 + (1.0f - f) * bf2f(uu.z);
      o[2] = xv.z + r * (c2 / (1.0f + fabsf(c2))) + (1.0f - r) * xnv;
    }
    {
      const float f = ff.w * (1.0f / 255.0f), r = rr.w * (1.0f / 255.0f);
      const float xnv = (xv.w - mu) * rs * gm.w + bt.w;
      c3 = f * c3 + (1.0f - f) * bf2f(uu.w);
      o[3] = xv.w + r * (c3 / (1.0f + fabsf(c3))) + (1.0f - r) * xnv;
    }
    *reinterpret_cast<float4*>(&out[xo]) = make_float4(o[0], o[1], o[2], o[3]);
    xo += BATCH * DIM;
    row += BATCH;
  }
}

extern "C" void kernel_launch(void* const* d_in, const int* in_sizes, int n_in,
                              void* d_out, int out_size, void* d_ws, size_t ws_size,
                              hipStream_t stream) {
  const float* x = (const float*)d_in[0];
  const float* c0 = (const float*)d_in[1];
  const float* w = (const float*)d_in[2];
  const float* gamma = (const float*)d_in[3];
  const float* beta = (const float*)d_in[4];
  float* out = (float*)d_out;
  float* clast = out + (size_t)M_SZ * DIM;   // second output, flat-concatenated

  // workspace layout (~110.2 MB)
  char* ws = (char*)d_ws;
  unsigned short* xn = (unsigned short*)ws;                        //  33,554,432 B
  unsigned short* U  = (unsigned short*)(ws + 33554432ull);        //  33,554,432 B
  unsigned char* Fq  = (unsigned char*)(ws + 67108864ull);         //  16,777,216 B
  unsigned char* Rq  = (unsigned char*)(ws + 83886080ull);         //  16,777,216 B
  float* Ac = (float*)(ws + 100663296ull);                         //   1,048,576 B
  float* Bc = (float*)(ws + 101711872ull);                         //   1,048,576 B
  float* cst = (float*)(ws + 102760448ull);                        //   1,048,576 B
  unsigned short* wb = (unsigned short*)(ws + 103809024ull);       //   6,291,456 B
  float* muA = (float*)(ws + 110100480ull);                        //      65,536 B
  float* rsA = (float*)(ws + 110166016ull);                        //      65,536 B

  cvt_kernel<<<(N_SZ * K_SZ / 4) / 256, 256, 0, stream>>>(w, wb);
  ln_kernel<<<M_SZ, 256, 0, stream>>>(x, gamma, beta, xn, muA, rsA);
  gemm_kernel<<<NWG, 512, 0, stream>>>(xn, wb, U, Fq, Rq);
  scan1_kernel<<<(NCHUNK * BATCH * DIM / 4) / 256, 256, 0, stream>>>(U, Fq, Ac, Bc);
  scan2_kernel<<<(BATCH * DIM) / 256, 256, 0, stream>>>(Ac, Bc, c0, cst, clast);
  scan3_kernel<<<(NCHUNK * BATCH * DIM / 4) / 256, 256, 0, stream>>>(
      U, Fq, Rq, x, cst, muA, rsA, gamma, beta, out);
}